// Round 9
// baseline (2025.983 us; speedup 1.0000x reference)
//
#include <hip/hip_runtime.h>

typedef unsigned short u16;
typedef unsigned int u32;
typedef u16 u16x8 __attribute__((ext_vector_type(8)));
typedef u16 u16x4 __attribute__((ext_vector_type(4)));
typedef __bf16 bf16x8 __attribute__((ext_vector_type(8)));
typedef float f32x4 __attribute__((ext_vector_type(4)));

#define O_N 50000
#define T_N 100000
#define HID 512
#define K1 384
#define BM 128
#define BN 128
#define BK 32
#define LDT 40  // padded LDS stride (u16); 16B-quad stride 5 (odd) -> conflict-free b128

#define OF_F32 1
#define OF_HI 2
#define OF_LO 4

__device__ __forceinline__ u16 f2bf(float f) {
  u32 u = __float_as_uint(f);
  u += 0x7fffu + ((u >> 16) & 1u);
  return (u16)(u >> 16);
}
__device__ __forceinline__ float bf2f(u16 b) {
  return __uint_as_float(((u32)b) << 16);
}
__device__ __forceinline__ f32x4 mfma16(u16x8 a, u16x8 b, f32x4 c) {
  return __builtin_amdgcn_mfma_f32_16x16x32_bf16(
      __builtin_bit_cast(bf16x8, a), __builtin_bit_cast(bf16x8, b), c, 0, 0, 0);
}
__device__ __forceinline__ float wave_sum(float v) {
#pragma unroll
  for (int m = 32; m >= 1; m >>= 1) v += __shfl_xor(v, m, 64);
  return v;
}

// C[M x N] = act(A @ B + bias_f32). B given as bf16 hi(+lo) planes in BT form [N][K].
// AMODE: 0 = A bf16; 1 = A fp32 rows, split in stage; 2 = gathered fp32 t_in rows;
//        3 = A bf16 hi/lo planes.
// BSPLIT: stage B lo plane, add Ah*Bl term.
// FUSE: M-phase epilogue over N=1152 (see round-7 comment).
// Grid is 1D = nx*NY blocks; m204 bijective XCD-chunk swizzle groups all NY
// y-blocks of one x-tile (shared A-rows) onto one XCD so its L2 dedupes the
// A fetch (hardware round-robins blockIdx%8 across XCDs).
template <int AMODE, int BSPLIT, int RELU, int OFLAGS, int FUSE>
__global__ __launch_bounds__(256) void gemm_k(
    const void* __restrict__ Ap, const u16* __restrict__ Apl,
    const u16* __restrict__ Bph, const u16* __restrict__ Bpl,
    const float* __restrict__ biasf,
    float* __restrict__ Cf, u16* __restrict__ Ch, u16* __restrict__ Cl,
    u16* __restrict__ Ch2,
    int M, int N, int K, int lda, int ldc, int NY,
    const int* __restrict__ edges, const float* __restrict__ objf,
    const float* __restrict__ predf, int r0,
    const u16* __restrict__ auxp, float* __restrict__ scoresp) {
  const bool ASPLIT = (AMODE == 1 || AMODE == 2 || AMODE == 3);
  __shared__ u16 Ah[BM * LDT];
  __shared__ u16 Al[(AMODE == 1 || AMODE == 2 || AMODE == 3) ? BM * LDT : 8];
  __shared__ u16 Bh[BN * LDT];
  __shared__ u16 Bl[BSPLIT ? BN * LDT : 8];

  const int tid = threadIdx.x;
  const int lane = tid & 63;
  const int wave = tid >> 6;
  const int wm = (wave >> 1) * 64;
  const int wn = (wave & 1) * 64;
  // ---- XCD-chunked bijective swizzle (m204): orig%8 = XCD; give each XCD a
  // contiguous span of logical tiles. Identity when nwg<=8.
  int wg;
  {
    int nwg = gridDim.x, orig = blockIdx.x;
    int q = nwg >> 3, r = nwg & 7;
    int xcd = orig & 7, idx = orig >> 3;
    wg = (xcd < r ? xcd * (q + 1) : r * (q + 1) + (xcd - r) * q) + idx;
  }
  const int m0 = (wg / NY) * BM;
  const int n0 = (wg % NY) * BN;
  const int sr = tid >> 1;        // staged tile row
  const int sh = (tid & 1) * 16;  // k-offset half

  f32x4 acc[4][4] = {};

  for (int k0 = 0; k0 < K; k0 += BK) {
    __syncthreads();
    // ---- stage A ----
    if (AMODE == 0) {
      u16x8 v0 = {0, 0, 0, 0, 0, 0, 0, 0}, v1 = {0, 0, 0, 0, 0, 0, 0, 0};
      if (m0 + sr < M) {
        const u16* src = (const u16*)Ap + (size_t)(m0 + sr) * lda + k0 + sh;
        v0 = *(const u16x8*)src;
        v1 = *(const u16x8*)(src + 8);
      }
      *(u16x8*)&Ah[sr * LDT + sh] = v0;
      *(u16x8*)&Ah[sr * LDT + sh + 8] = v1;
    } else if (AMODE == 3) {
      u16x8 h0 = {0, 0, 0, 0, 0, 0, 0, 0}, h1 = h0, l0 = h0, l1 = h0;
      if (m0 + sr < M) {
        size_t base = (size_t)(m0 + sr) * lda + k0 + sh;
        h0 = *(const u16x8*)((const u16*)Ap + base);
        h1 = *(const u16x8*)((const u16*)Ap + base + 8);
        l0 = *(const u16x8*)(Apl + base);
        l1 = *(const u16x8*)(Apl + base + 8);
      }
      *(u16x8*)&Ah[sr * LDT + sh] = h0;
      *(u16x8*)&Ah[sr * LDT + sh + 8] = h1;
      *(u16x8*)&Al[sr * LDT + sh] = l0;
      *(u16x8*)&Al[sr * LDT + sh + 8] = l1;
    } else {  // AMODE 1 or 2: fp32 source, split into hi/lo
      float vals[16];
      if (m0 + sr < M) {
        const float* src;
        if (AMODE == 1) {
          src = (const float*)Ap + (size_t)(m0 + sr) * lda + k0 + sh;
        } else {
          int gr = r0 + m0 + sr;
          int col = k0 + sh;  // 16-col segment inside one source (128|128|128)
          if (col < 128) src = objf + (size_t)edges[gr * 2] * 128 + col;
          else if (col < 256) src = predf + (size_t)gr * 128 + (col - 128);
          else src = objf + (size_t)edges[gr * 2 + 1] * 128 + (col - 256);
        }
        const f32x4* s4 = (const f32x4*)src;
        f32x4 a0 = s4[0], a1 = s4[1], a2 = s4[2], a3 = s4[3];
#pragma unroll
        for (int i = 0; i < 4; i++) {
          vals[i] = a0[i]; vals[4 + i] = a1[i]; vals[8 + i] = a2[i]; vals[12 + i] = a3[i];
        }
      } else {
#pragma unroll
        for (int i = 0; i < 16; i++) vals[i] = 0.f;
      }
      u16x8 h0, h1, l0, l1;
#pragma unroll
      for (int i = 0; i < 8; i++) {
        u16 hb = f2bf(vals[i]);
        h0[i] = hb; l0[i] = f2bf(vals[i] - bf2f(hb));
        u16 hb2 = f2bf(vals[8 + i]);
        h1[i] = hb2; l1[i] = f2bf(vals[8 + i] - bf2f(hb2));
      }
      *(u16x8*)&Ah[sr * LDT + sh] = h0;
      *(u16x8*)&Ah[sr * LDT + sh + 8] = h1;
      *(u16x8*)&Al[sr * LDT + sh] = l0;
      *(u16x8*)&Al[sr * LDT + sh + 8] = l1;
    }
    // ---- stage B ----
    {
      size_t base = (size_t)(n0 + sr) * K + k0 + sh;
      u16x8 b0 = *(const u16x8*)(Bph + base);
      u16x8 b1 = *(const u16x8*)(Bph + base + 8);
      *(u16x8*)&Bh[sr * LDT + sh] = b0;
      *(u16x8*)&Bh[sr * LDT + sh + 8] = b1;
      if (BSPLIT) {
        u16x8 c0 = *(const u16x8*)(Bpl + base);
        u16x8 c1 = *(const u16x8*)(Bpl + base + 8);
        *(u16x8*)&Bl[sr * LDT + sh] = c0;
        *(u16x8*)&Bl[sr * LDT + sh + 8] = c1;
      }
    }
    __syncthreads();
    // ---- fragments + MFMA ----
    const int fr = lane & 15;
    const int q8 = (lane >> 4) * 8;
    u16x8 af[4], bf[4];
#pragma unroll
    for (int i = 0; i < 4; i++) af[i] = *(const u16x8*)&Ah[(wm + i * 16 + fr) * LDT + q8];
#pragma unroll
    for (int j = 0; j < 4; j++) bf[j] = *(const u16x8*)&Bh[(wn + j * 16 + fr) * LDT + q8];
#pragma unroll
    for (int i = 0; i < 4; i++)
#pragma unroll
      for (int j = 0; j < 4; j++) acc[i][j] = mfma16(af[i], bf[j], acc[i][j]);
    if (ASPLIT) {
      u16x8 alf[4];
#pragma unroll
      for (int i = 0; i < 4; i++) alf[i] = *(const u16x8*)&Al[(wm + i * 16 + fr) * LDT + q8];
#pragma unroll
      for (int i = 0; i < 4; i++)
#pragma unroll
        for (int j = 0; j < 4; j++) acc[i][j] = mfma16(alf[i], bf[j], acc[i][j]);
    }
    if (BSPLIT) {
      u16x8 blf[4];
#pragma unroll
      for (int j = 0; j < 4; j++) blf[j] = *(const u16x8*)&Bl[(wn + j * 16 + fr) * LDT + q8];
#pragma unroll
      for (int i = 0; i < 4; i++)
#pragma unroll
        for (int j = 0; j < 4; j++) acc[i][j] = mfma16(af[i], blf[j], acc[i][j]);
    }
  }
  // ---- epilogue: C/D layout col=lane&15, row=(lane>>4)*4+reg (m89/m91 verified) ----
  const int fc = lane & 15;
  const int fr4 = (lane >> 4) * 4;
  if (FUSE) {
    // side: n0<512 -> S (0), n0==512 -> P (-1), n0>=640 -> O (1). Uniform per block.
    const int side = (n0 >= 640) ? 1 : (n0 < 512 ? 0 : -1);
    const int cb = n0 + wn + fc;
    float bvs[4];
#pragma unroll
    for (int j = 0; j < 4; j++) bvs[j] = biasf[cb + j * 16];
    __syncthreads();                 // staging LDS now dead; reuse Ah for score buf
    float* scb = (float*)Ah;         // [128 rows][2 wn-slots]
#pragma unroll
    for (int i = 0; i < 4; i++) {
#pragma unroll
      for (int rr = 0; rr < 4; rr++) {
        int rl = wm + i * 16 + fr4 + rr;
        int row = m0 + rl;
        float sc = 0.f;
        if (row < M) {
          const u16* arow = nullptr;
          if (side == 0) arow = auxp + (size_t)edges[(size_t)(r0 + row) * 2] * 512;
          else if (side == 1) arow = auxp + (size_t)edges[(size_t)(r0 + row) * 2 + 1] * 512;
#pragma unroll
          for (int j = 0; j < 4; j++) {
            int col = cb + j * 16;
            float v = acc[i][j][rr] + bvs[j];
            v = fmaxf(v, 0.f);
            if (side < 0) {
              Cf[(size_t)row * 128 + (col - 512)] = v;
            } else {
              int cc = col - (side ? 640 : 0);
              size_t ci = (size_t)row * 512 + cc;
              if (side) Ch2[ci] = f2bf(v);
              else Ch[ci] = f2bf(v);
              sc += v * bf2f(arow[cc]);
            }
          }
        }
        if (side >= 0) {
#pragma unroll
          for (int mm = 1; mm <= 8; mm <<= 1) sc += __shfl_xor(sc, mm, 64);
          if (fc == 0) scb[rl * 2 + (wn ? 1 : 0)] = sc;
        }
      }
    }
    __syncthreads();
    if (side >= 0 && tid < 128) {
      int row = m0 + tid;
      if (row < M) {
        float s = scb[tid * 2] + scb[tid * 2 + 1];
        atomicAdd(&scoresp[(side ? T_N : 0) + (r0 + row)], s);
      }
    }
    return;
  }
#pragma unroll
  for (int j = 0; j < 4; j++) {
    int col = n0 + wn + j * 16 + fc;
    float bv = biasf ? biasf[col] : 0.f;
#pragma unroll
    for (int i = 0; i < 4; i++) {
      int rbase = m0 + wm + i * 16 + fr4;
#pragma unroll
      for (int rr = 0; rr < 4; rr++) {
        int row = rbase + rr;
        if (row < M) {
          float v = acc[i][j][rr] + bv;
          if (RELU) v = fmaxf(v, 0.f);
          size_t ci = (size_t)row * ldc + col;
          if (OFLAGS & OF_F32) Cf[ci] = v;
          if (OFLAGS & OF_HI) {
            u16 h = f2bf(v);
            Ch[ci] = h;
            if (OFLAGS & OF_LO) Cl[ci] = f2bf(v - bf2f(h));
          }
        }
      }
    }
  }
}

// fp32 [K][N] -> bf16 hi(+lo) planes in BT form [N][K]. outl may be null.
__global__ void k_convT(const float* __restrict__ in, u16* __restrict__ outh,
                        u16* __restrict__ outl, int K, int N) {
  int idx = blockIdx.x * 256 + threadIdx.x;
  if (idx >= K * N) return;
  int n = idx / K, k = idx % K;
  float v = in[(size_t)k * N + n];
  u16 h = f2bf(v);
  outh[idx] = h;
  if (outl) outl[idx] = f2bf(v - bf2f(h));
}

// fp32 -> bf16 hi/lo planes, elementwise
__global__ void k_conv(const float* __restrict__ in, u16* __restrict__ outh,
                       u16* __restrict__ outl, int n) {
  int idx = blockIdx.x * 256 + threadIdx.x;
  if (idx >= n) return;
  float v = in[idx];
  u16 h = f2bf(v);
  outh[idx] = h;
  if (outl) outl[idx] = f2bf(v - bf2f(h));
}

// gather t_in rows [obj[s]|pred|obj[o]] -> bf16 hi/lo planes, chunk-local.
// 4 elems/thread (f32x4 load, u16x4 plane stores). Same f2bf round points as the
// old AMODE-2 staging -> h1 stays bitwise identical.
__global__ void k_gather(const float* __restrict__ objf, const float* __restrict__ predf,
                         const int* __restrict__ edges, u16* __restrict__ tinH,
                         u16* __restrict__ tinL, int r0, int rows) {
  int idx = blockIdx.x * 256 + threadIdx.x;
  if (idx >= rows * 96) return;
  int r = idx / 96, c4 = (idx - r * 96) * 4;
  int gr = r0 + r;
  const float* src;
  if (c4 < 128) src = objf + (size_t)edges[gr * 2] * 128 + c4;
  else if (c4 < 256) src = predf + (size_t)gr * 128 + (c4 - 128);
  else src = objf + (size_t)edges[gr * 2 + 1] * 128 + (c4 - 256);
  f32x4 v = *(const f32x4*)src;
  u16x4 hv, lv;
#pragma unroll
  for (int k = 0; k < 4; k++) {
    u16 h = f2bf(v[k]);
    hv[k] = h;
    lv[k] = f2bf(v[k] - bf2f(h));
  }
  size_t base = (size_t)r * K1 + c4;
  *(u16x4*)(tinH + base) = hv;
  *(u16x4*)(tinL + base) = lv;
}

// ---- weight folding (all fp32, trivial FLOPs) ----
__global__ void k_foldb1(const float* __restrict__ bp, const float* __restrict__ Ws,
                         const float* __restrict__ bs, float* __restrict__ bf1) {
  int n = blockIdx.x * 256 + threadIdx.x;
  if (n >= HID) return;
  float s = bs[n];
  for (int k = 0; k < HID; k++) s += bp[k] * Ws[(size_t)k * HID + n];
  bf1[n] = s;
}
__global__ void k_foldba(const float* __restrict__ bf1, const float* __restrict__ Ws,
                         float* __restrict__ ba) {
  int n = blockIdx.x * 256 + threadIdx.x;
  if (n >= HID) return;
  float s = 0.f;
  for (int k = 0; k < HID; k++) s += bf1[k] * Ws[(size_t)n * HID + k];
  ba[n] = s;
}
__global__ void k_foldwz(const float* __restrict__ Wf, const float* __restrict__ bs,
                         const float* __restrict__ bf1, float* __restrict__ wz,
                         float* __restrict__ bz) {
  int m = blockIdx.x * 256 + threadIdx.x;
  if (m < 128) {
    float s = 0.f;
    for (int n = 0; n < HID; n++) s += Wf[(size_t)m * HID + n] * bs[n];
    wz[m] = s;
  }
  if (m == 128) {
    float s = 0.f;
    for (int n = 0; n < HID; n++) s += bf1[n] * bs[n];
    *bz = s;
  }
}
// zs[o] = obj[o].wz + bz
__global__ void k_zsm(const float* __restrict__ obj, const float* __restrict__ wz,
                      const float* __restrict__ bz, float* __restrict__ zs, int rows) {
  int o = blockIdx.x * 4 + (threadIdx.x >> 6);
  int lane = threadIdx.x & 63;
  if (o >= rows) return;
  const float2* row = (const float2*)(obj + (size_t)o * 128);
  float2 v = row[lane];
  float2 w = ((const float2*)wz)[lane];
  float d = v.x * w.x + v.y * w.y;
  d = wave_sum(d);
  if (lane == 0) zs[o] = d + *bz;
}

__global__ void k_count(const int* __restrict__ edges, int* __restrict__ cnt) {
  int e = blockIdx.x * 256 + threadIdx.x;
  if (e >= 2 * T_N) return;
  int c = (e < T_N) ? edges[e * 2 + 0] : edges[(e - T_N) * 2 + 1];
  atomicAdd(cnt + c, 1);
}

__global__ void k_scan_a(const int* __restrict__ cnt, int* __restrict__ incl,
                         int* __restrict__ bsum) {
  __shared__ int sb[1024];
  int i = blockIdx.x * 1024 + threadIdx.x;
  int v = (i < O_N) ? cnt[i] : 0;
  sb[threadIdx.x] = v;
  __syncthreads();
  for (int ofs = 1; ofs < 1024; ofs <<= 1) {
    int t = (threadIdx.x >= ofs) ? sb[threadIdx.x - ofs] : 0;
    __syncthreads();
    sb[threadIdx.x] += t;
    __syncthreads();
  }
  if (i < O_N) incl[i] = sb[threadIdx.x];
  if (threadIdx.x == 1023) bsum[blockIdx.x] = sb[1023];
}

__global__ void k_scan_b(const int* __restrict__ bsum, int* __restrict__ bpre, int nb) {
  if (threadIdx.x == 0 && blockIdx.x == 0) {
    int run = 0;
    for (int b = 0; b < nb; b++) { bpre[b] = run; run += bsum[b]; }
  }
}

__global__ void k_scan_c(const int* __restrict__ incl, const int* __restrict__ cnt,
                         const int* __restrict__ bpre, int* __restrict__ excl,
                         int* __restrict__ cursor) {
  int i = blockIdx.x * 1024 + threadIdx.x;
  if (i >= O_N) return;
  int ex = incl[i] - cnt[i] + bpre[blockIdx.x];
  excl[i] = ex;
  cursor[i] = ex;
}

__global__ void k_fill(const int* __restrict__ edges, int* __restrict__ cursor,
                       int* __restrict__ csr) {
  int e = blockIdx.x * 256 + threadIdx.x;
  if (e >= 2 * T_N) return;
  int c = (e < T_N) ? edges[e * 2 + 0] : edges[(e - T_N) * 2 + 1];
  int pos = atomicAdd(cursor + c, 1);
  csr[pos] = e;
}

// scores[e] = zs[cand_idx[e]]  (base for fused-epilogue atomic accumulation)
__global__ void k_sinit(const int* __restrict__ edges, const float* __restrict__ zs,
                        float* __restrict__ scores) {
  int e = blockIdx.x * 256 + threadIdx.x;
  if (e >= 2 * T_N) return;
  int c = (e < T_N) ? edges[e * 2 + 0] : edges[(e - T_N) * 2 + 1];
  scores[e] = zs[c];
}

// score fix: scores[e] += cand_hi . (auxf - auxhi), per O-chunk
__global__ void k_fix(const u16* __restrict__ newShi, const u16* __restrict__ newOhi,
                      const u16* __restrict__ auxhi, const float* __restrict__ auxf,
                      const int* __restrict__ csr, const int* __restrict__ excl,
                      const int* __restrict__ cnt, float* __restrict__ scores,
                      int q0, int rows) {
  int ol = blockIdx.x * 4 + (threadIdx.x >> 6);
  int lane = threadIdx.x & 63;
  if (ol >= rows) return;
  int o = q0 + ol;
  int off = excl[o], deg = cnt[o];
  if (deg == 0) return;
  const f32x4* afp = (const f32x4*)(auxf + (size_t)ol * HID + lane * 8);
  f32x4 af0 = afp[0], af1 = afp[1];
  u16x8 ah = *(const u16x8*)(auxhi + (size_t)o * HID + lane * 8);
  float al[8];
#pragma unroll
  for (int k = 0; k < 4; k++) {
    al[k] = af0[k] - bf2f(ah[k]);
    al[4 + k] = af1[k] - bf2f(ah[4 + k]);
  }
  for (int i = 0; i < deg; i++) {
    int e = csr[off + i];
    const u16* cand =
        (e < T_N) ? newShi + (size_t)e * HID : newOhi + (size_t)(e - T_N) * HID;
    u16x8 ch = *(const u16x8*)(cand + lane * 8);
    float d = 0.f;
#pragma unroll
    for (int k = 0; k < 8; k++) d += bf2f(ch[k]) * al[k];
    d = wave_sum(d);
    if (lane == 0) scores[e] += d;  // each edge owned by exactly one object: no race
  }
}

// pool -> bf16 hi/lo planes (identical f2bf round points as the AMODE1 stage path)
__global__ void k_pool(const u16* __restrict__ newShi, const u16* __restrict__ newOhi,
                       const float* __restrict__ scores, const float* __restrict__ zs,
                       const int* __restrict__ csr, const int* __restrict__ excl,
                       const int* __restrict__ cnt, u16* __restrict__ pooledH,
                       u16* __restrict__ pooledL, int q0, int rows) {
  int ol = blockIdx.x * 4 + (threadIdx.x >> 6);
  int lane = threadIdx.x & 63;
  if (ol >= rows) return;
  int o = q0 + ol;
  int off = excl[o], deg = cnt[o];
  float zso = zs[o];
  float m = zso;
  for (int base = 0; base < deg; base += 64) {
    float s = (base + lane < deg) ? scores[csr[off + base + lane]] : -3.4e38f;
    m = fmaxf(m, s);
  }
#pragma unroll
  for (int x = 32; x >= 1; x >>= 1) m = fmaxf(m, __shfl_xor(m, x, 64));
  float denom = __expf(zso - m);
  float acc[8] = {0, 0, 0, 0, 0, 0, 0, 0};
  for (int i = 0; i < deg; i++) {
    int e = csr[off + i];
    float w = __expf(scores[e] - m);
    denom += w;
    const u16* cand =
        (e < T_N) ? newShi + (size_t)e * HID : newOhi + (size_t)(e - T_N) * HID;
    u16x8 cv = *(const u16x8*)(cand + lane * 8);
#pragma unroll
    for (int k = 0; k < 8; k++) acc[k] += w * bf2f(cv[k]);
  }
  float inv = 1.0f / denom;
  u16x8 ph, pl;
#pragma unroll
  for (int k = 0; k < 8; k++) {
    float v = acc[k] * inv;
    u16 h = f2bf(v);
    ph[k] = h;
    pl[k] = f2bf(v - bf2f(h));
  }
  *(u16x8*)(pooledH + (size_t)ol * HID + lane * 8) = ph;
  *(u16x8*)(pooledL + (size_t)ol * HID + lane * 8) = pl;
}

extern "C" void kernel_launch(void* const* d_in, const int* in_sizes, int n_in,
                              void* d_out, int out_size, void* d_ws, size_t ws_size,
                              hipStream_t stream) {
  const float* objf = (const float*)d_in[0];
  const float* predf = (const float*)d_in[1];
  const int* edges = (const int*)d_in[2];
  const float* n1w1f = (const float*)d_in[3];
  const float* n1b1f = (const float*)d_in[4];
  const float* n1w2f = (const float*)d_in[5];
  const float* n1b2f = (const float*)d_in[6];
  const float* n2w1f = (const float*)d_in[7];
  const float* n2b1f = (const float*)d_in[8];
  const float* n2w2f = (const float*)d_in[9];
  const float* n2b2f = (const float*)d_in[10];
  const float* projwf = (const float*)d_in[11];
  const float* projbf = (const float*)d_in[12];
  const float* simwf = (const float*)d_in[13];
  const float* simbf = (const float*)d_in[14];

  float* out_obj = (float*)d_out;                    // O x 128 fp32
  float* out_p = (float*)d_out + (size_t)O_N * 128;  // T x 128 fp32

  // ---- folded weights + fused M gemm + hoisted t_in gather ----
  const long long FIXED = 267000000ll;
  long long budget = (long long)ws_size - FIXED;
  if (budget < 5000000ll) budget = 5000000ll;
  int rT, rOb, rFx;
  {
    // arena per T-row: tin planes (K1*2*2=1536) + h1 planes (2048) = 3584 B
    long long r = budget / 3584; if (r > 50048) r = 50048; if (r < 1280) r = 1280;
    int n = (int)((T_N + r - 1) / r);
    rT = ((T_N + n - 1) / n + 127) & ~127;
  }
  {
    long long r = budget / 3072; if (r > 25024) r = 25024; if (r < 1280) r = 1280;
    int n = (int)((O_N + r - 1) / r);
    rOb = ((O_N + n - 1) / n + 127) & ~127;
  }
  {
    long long r = budget / 2048; if (r > 25024) r = 25024; if (r < 1280) r = 1280;
    int n = (int)((O_N + r - 1) / r);
    rFx = ((O_N + n - 1) / n + 127) & ~127;
  }
  const int nT = (T_N + rT - 1) / rT;
  const int nOb = (O_N + rOb - 1) / rOb;
  const int nFx = (O_N + rFx - 1) / rFx;
  size_t arena_sz = (size_t)rT * 3584;  // tinH+tinL + h1H+h1L
  if ((size_t)rFx * 2048 > arena_sz) arena_sz = (size_t)rFx * 2048;
  if ((size_t)rOb * 3072 > arena_sz) arena_sz = (size_t)rOb * 3072;
  arena_sz = (arena_sz + 4095) & ~(size_t)4095;

  char* ws = (char*)d_ws;
  size_t off = 0;
  u16* newShi = (u16*)(ws + off); off += (size_t)T_N * HID * 2;  // 102.4 MB
  u16* newOhi = (u16*)(ws + off); off += (size_t)T_N * HID * 2;  // 102.4 MB
  u16* auxhi = (u16*)(ws + off);  off += (size_t)O_N * HID * 2;  // 51.2 MB
  char* arena = ws + off; off += arena_sz;

  // phase M views: tin planes then h1 planes
  u16* tinH = (u16*)arena;
  u16* tinL = (u16*)(arena + (size_t)rT * 768);
  u16* h1H = (u16*)(arena + (size_t)rT * 1536);
  u16* h1L = (u16*)(arena + (size_t)rT * 1536 + (size_t)rT * 1024);
  // fix-phase view
  float* auxfC = (float*)arena;
  // phase C views
  u16* pooledH = (u16*)arena;
  u16* pooledL = (u16*)(arena + (size_t)rOb * 1024);
  u16* h2c = (u16*)(arena + (size_t)rOb * 2048);

  float* scoresb = (float*)(ws + off); off += (size_t)2 * T_N * 4;
  float* zsb = (float*)(ws + off); off += (size_t)O_N * 4;
  int* cnt = (int*)(ws + off); off += (size_t)O_N * 4;
  int* incl = (int*)(ws + off); off += (size_t)O_N * 4;
  int* excl = (int*)(ws + off); off += (size_t)O_N * 4;
  int* cursor = (int*)(ws + off); off += (size_t)O_N * 4;
  int* csr = (int*)(ws + off); off += (size_t)2 * T_N * 4;
  int* bsum = (int*)(ws + off); off += 4096;
  int* bpre = (int*)(ws + off); off += 4096;
  u16* w1TH = (u16*)(ws + off); off += (size_t)K1 * HID * 2;
  u16* w1TL = (u16*)(ws + off); off += (size_t)K1 * HID * 2;
  u16* w2TH = (u16*)(ws + off); off += (size_t)1152 * HID * 2;
  u16* w2TL = (u16*)(ws + off); off += (size_t)1152 * HID * 2;
  u16* swTH = (u16*)(ws + off); off += (size_t)HID * HID * 2;
  u16* swTL = (u16*)(ws + off); off += (size_t)HID * HID * 2;
  u16* swRH = (u16*)(ws + off); off += (size_t)HID * HID * 2;
  u16* swRL = (u16*)(ws + off); off += (size_t)HID * HID * 2;
  u16* a2TH = (u16*)(ws + off); off += (size_t)HID * HID * 2;
  u16* a2TL = (u16*)(ws + off); off += (size_t)HID * HID * 2;
  u16* b2TH = (u16*)(ws + off); off += (size_t)128 * HID * 2;
  u16* b2TL = (u16*)(ws + off); off += (size_t)128 * HID * 2;
  float* Wf = (float*)(ws + off);  off += (size_t)128 * HID * 4;  // Wp@Ws
  float* Waf = (float*)(ws + off); off += (size_t)128 * HID * 4;  // Wf@Ws^T
  u16* WaTH = (u16*)(ws + off); off += (size_t)HID * 128 * 2;
  u16* WaTL = (u16*)(ws + off); off += (size_t)HID * 128 * 2;
  float* bf1 = (float*)(ws + off); off += 2048;
  float* baf = (float*)(ws + off); off += 2048;
  float* wzf = (float*)(ws + off); off += 512;
  float* bzf = (float*)(ws + off); off += 16;

  hipMemsetAsync(cnt, 0, O_N * sizeof(int), stream);

  // ---- weight planes ----
  k_convT<<<768, 256, 0, stream>>>(n1w1f, w1TH, w1TL, K1, HID);
  k_convT<<<2304, 256, 0, stream>>>(n1w2f, w2TH, w2TL, HID, 1152);
  k_convT<<<1024, 256, 0, stream>>>(simwf, swTH, swTL, HID, HID);
  k_conv<<<1024, 256, 0, stream>>>(simwf, swRH, swRL, HID * HID);  // Ws^T in BT form
  k_convT<<<1024, 256, 0, stream>>>(n2w1f, a2TH, a2TL, HID, HID);
  k_convT<<<256, 256, 0, stream>>>(n2w2f, b2TH, b2TL, HID, 128);

  // ---- CSR of cand_idx ----
  k_count<<<782, 256, 0, stream>>>(edges, cnt);
  k_scan_a<<<49, 1024, 0, stream>>>(cnt, incl, bsum);
  k_scan_b<<<1, 64, 0, stream>>>(bsum, bpre, 49);
  k_scan_c<<<49, 1024, 0, stream>>>(incl, cnt, bpre, excl, cursor);
  k_fill<<<782, 256, 0, stream>>>(edges, cursor, csr);

  // ---- weight folding ----
  {
    gemm_k<1, 1, 0, OF_F32, 0><<<4, 256, 0, stream>>>(
        projwf, nullptr, swTH, swTL, nullptr,
        Wf, nullptr, nullptr, nullptr,
        128, HID, HID, HID, HID, 4, nullptr, nullptr, nullptr, 0, nullptr, nullptr);
    gemm_k<1, 1, 0, OF_F32, 0><<<4, 256, 0, stream>>>(
        Wf, nullptr, swRH, swRL, nullptr,
        Waf, nullptr, nullptr, nullptr,
        128, HID, HID, HID, HID, 4, nullptr, nullptr, nullptr, 0, nullptr, nullptr);
    k_convT<<<256, 256, 0, stream>>>(Waf, WaTH, WaTL, 128, HID);
    k_foldb1<<<2, 256, 0, stream>>>(projbf, simwf, simbf, bf1);
    k_foldba<<<2, 256, 0, stream>>>(bf1, simwf, baf);
    k_foldwz<<<1, 256, 0, stream>>>(Wf, simbf, bf1, wzf, bzf);
  }

  // ---- phase B1 (folded): one full-grid gemm obj -> auxhi, plus zs matvec ----
  {
    int gx = (O_N + BM - 1) / BM;
    gemm_k<1, 1, 0, OF_HI, 0><<<gx * 4, 256, 0, stream>>>(
        objf, nullptr, WaTH, WaTL, baf,
        nullptr, auxhi, nullptr, nullptr,
        O_N, HID, 128, 128, HID, 4, nullptr, nullptr, nullptr, 0, nullptr, nullptr);
    k_zsm<<<(O_N + 3) / 4, 256, 0, stream>>>(objf, wzf, bzf, zsb, O_N);
  }

  // ---- scores base = zs[cand] (fused epilogues accumulate on top) ----
  k_sinit<<<782, 256, 0, stream>>>(edges, zsb, scoresb);

  // ---- phase M: gather -> MLP1 (planes gemm) -> fused N=1152 gemm w/ scores ----
  for (int ci = 0; ci < nT; ci++) {
    int r0 = ci * rT;
    int rows = (r0 + rT <= T_N) ? rT : (T_N - r0);
    int gx = (rows + BM - 1) / BM;
    k_gather<<<(rows * 96 + 255) / 256, 256, 0, stream>>>(
        objf, predf, edges, tinH, tinL, r0, rows);
    gemm_k<3, 1, 1, OF_HI | OF_LO, 0><<<gx * 4, 256, 0, stream>>>(
        tinH, tinL, w1TH, w1TL, n1b1f,
        nullptr, h1H, h1L, nullptr,
        rows, HID, K1, K1, HID, 4, nullptr, nullptr, nullptr, 0, nullptr, nullptr);
    // fused: 0-511 -> newShi, 512-639 -> out_p, 640-1151 -> newOhi; scores atomic
    gemm_k<3, 1, 1, 0, 1><<<gx * 9, 256, 0, stream>>>(
        h1H, h1L, w2TH, w2TL, n1b2f,
        out_p + (size_t)r0 * 128, newShi + (size_t)r0 * HID, nullptr,
        newOhi + (size_t)r0 * HID,
        rows, 1152, HID, HID, HID, 9, edges, nullptr, nullptr, r0, auxhi, scoresb);
  }

  // ---- score fix: folded fp32 aux per O-chunk ----
  for (int ci = 0; ci < nFx; ci++) {
    int q0 = ci * rFx;
    int rows = (q0 + rFx <= O_N) ? rFx : (O_N - q0);
    int gx = (rows + BM - 1) / BM;
    gemm_k<1, 1, 0, OF_F32, 0><<<gx * 4, 256, 0, stream>>>(
        objf + (size_t)q0 * 128, nullptr, WaTH, WaTL, baf,
        auxfC, nullptr, nullptr, nullptr,
        rows, HID, 128, 128, HID, 4, nullptr, nullptr, nullptr, 0, nullptr, nullptr);
    k_fix<<<(rows + 3) / 4, 256, 0, stream>>>(
        newShi, newOhi, auxhi, auxfC, csr, excl, cnt, scoresb, q0, rows);
  }

  // ---- phase C: pool (bf16 planes) -> MLP2, O-chunks ----
  for (int ci = 0; ci < nOb; ci++) {
    int q0 = ci * rOb;
    int rows = (q0 + rOb <= O_N) ? rOb : (O_N - q0);
    int gx = (rows + BM - 1) / BM;
    k_pool<<<(rows + 3) / 4, 256, 0, stream>>>(
        newShi, newOhi, scoresb, zsb, csr, excl, cnt, pooledH, pooledL, q0, rows);
    gemm_k<3, 1, 1, OF_HI, 0><<<gx * 4, 256, 0, stream>>>(
        pooledH, pooledL, a2TH, a2TL, n2b1f,
        nullptr, h2c, nullptr, nullptr,
        rows, HID, HID, HID, HID, 4, nullptr, nullptr, nullptr, 0, nullptr, nullptr);
    gemm_k<0, 1, 1, OF_F32, 0><<<gx, 256, 0, stream>>>(
        h2c, nullptr, b2TH, b2TL, n2b2f,
        out_obj + (size_t)q0 * 128, nullptr, nullptr, nullptr,
        rows, 128, HID, HID, 128, 1, nullptr, nullptr, nullptr, 0, nullptr, nullptr);
  }

  (void)in_sizes; (void)n_in; (void)out_size;
}

// Round 10
// 1886.081 us; speedup vs baseline: 1.0742x; 1.0742x over previous
//
#include <hip/hip_runtime.h>

typedef unsigned short u16;
typedef unsigned int u32;
typedef u16 u16x8 __attribute__((ext_vector_type(8)));
typedef __bf16 bf16x8 __attribute__((ext_vector_type(8)));
typedef float f32x4 __attribute__((ext_vector_type(4)));

#define O_N 50000
#define T_N 100000
#define HID 512
#define K1 384
#define BM 128
#define BN 128
#define BK 32
#define LDT 40  // padded LDS stride (u16); 16B-quad stride 5 (odd) -> conflict-free b128

#define OF_F32 1
#define OF_HI 2
#define OF_LO 4

__device__ __forceinline__ u16 f2bf(float f) {
  u32 u = __float_as_uint(f);
  u += 0x7fffu + ((u >> 16) & 1u);
  return (u16)(u >> 16);
}
__device__ __forceinline__ float bf2f(u16 b) {
  return __uint_as_float(((u32)b) << 16);
}
__device__ __forceinline__ f32x4 mfma16(u16x8 a, u16x8 b, f32x4 c) {
  return __builtin_amdgcn_mfma_f32_16x16x32_bf16(
      __builtin_bit_cast(bf16x8, a), __builtin_bit_cast(bf16x8, b), c, 0, 0, 0);
}
__device__ __forceinline__ float wave_sum(float v) {
#pragma unroll
  for (int m = 32; m >= 1; m >>= 1) v += __shfl_xor(v, m, 64);
  return v;
}

// C[M x N] = act(A @ B + bias_f32). B given as bf16 hi(+lo) planes in BT form [N][K].
// AMODE: 0 = A bf16; 1 = A fp32 rows (reg-prefetched, split in stage); 2 = gathered
//        fp32 t_in rows (reg-prefetched); 3 = A bf16 hi/lo planes.
// BSPLIT: stage B lo plane, add Ah*Bl term.
// FUSE: M-phase epilogue over N=1152 (S|P|O split + in-epilogue edge scores).
// Grid is 1D = nx*NY; m204 bijective XCD-chunk swizzle groups all NY y-blocks of
// one x-tile (shared A-rows) onto one XCD so its L2 dedupes the A fetch.
// AMODE 1/2 staging is software-pipelined: fp32 loads for step k0+BK issue right
// after the LDS write of step k0, hiding gather latency under stageB+barrier+MFMA.
template <int AMODE, int BSPLIT, int RELU, int OFLAGS, int FUSE>
__global__ __launch_bounds__(256) void gemm_k(
    const void* __restrict__ Ap, const u16* __restrict__ Apl,
    const u16* __restrict__ Bph, const u16* __restrict__ Bpl,
    const float* __restrict__ biasf,
    float* __restrict__ Cf, u16* __restrict__ Ch, u16* __restrict__ Cl,
    u16* __restrict__ Ch2,
    int M, int N, int K, int lda, int ldc, int NY,
    const int* __restrict__ edges, const float* __restrict__ objf,
    const float* __restrict__ predf, int r0,
    const u16* __restrict__ auxp, float* __restrict__ scoresp) {
  const bool ASPLIT = (AMODE == 1 || AMODE == 2 || AMODE == 3);
  __shared__ u16 Ah[BM * LDT];
  __shared__ u16 Al[(AMODE == 1 || AMODE == 2 || AMODE == 3) ? BM * LDT : 8];
  __shared__ u16 Bh[BN * LDT];
  __shared__ u16 Bl[BSPLIT ? BN * LDT : 8];

  const int tid = threadIdx.x;
  const int lane = tid & 63;
  const int wave = tid >> 6;
  const int wm = (wave >> 1) * 64;
  const int wn = (wave & 1) * 64;
  // ---- XCD-chunked bijective swizzle (m204) ----
  int wg;
  {
    int nwg = gridDim.x, orig = blockIdx.x;
    int q = nwg >> 3, r = nwg & 7;
    int xcd = orig & 7, idx = orig >> 3;
    wg = (xcd < r ? xcd * (q + 1) : r * (q + 1) + (xcd - r) * q) + idx;
  }
  const int m0 = (wg / NY) * BM;
  const int n0 = (wg % NY) * BN;
  const int sr = tid >> 1;        // staged tile row
  const int sh = (tid & 1) * 16;  // k-offset half

  f32x4 acc[4][4] = {};

  // ---- reg-prefetch state for fp32 A modes (1/2) ----
  float vals[16];
  auto loadA = [&](int kk) {
    if (m0 + sr < M) {
      const float* src;
      if (AMODE == 1) {
        src = (const float*)Ap + (size_t)(m0 + sr) * lda + kk + sh;
      } else {
        int gr = r0 + m0 + sr;
        int col = kk + sh;  // 16-col segment inside one source (128|128|128)
        if (col < 128) src = objf + (size_t)edges[gr * 2] * 128 + col;
        else if (col < 256) src = predf + (size_t)gr * 128 + (col - 128);
        else src = objf + (size_t)edges[gr * 2 + 1] * 128 + (col - 256);
      }
      const f32x4* s4 = (const f32x4*)src;
      f32x4 a0 = s4[0], a1 = s4[1], a2 = s4[2], a3 = s4[3];
#pragma unroll
      for (int i = 0; i < 4; i++) {
        vals[i] = a0[i]; vals[4 + i] = a1[i]; vals[8 + i] = a2[i]; vals[12 + i] = a3[i];
      }
    } else {
#pragma unroll
      for (int i = 0; i < 16; i++) vals[i] = 0.f;
    }
  };
  if (AMODE == 1 || AMODE == 2) loadA(0);

  for (int k0 = 0; k0 < K; k0 += BK) {
    __syncthreads();
    // ---- stage A ----
    if (AMODE == 0) {
      u16x8 v0 = {0, 0, 0, 0, 0, 0, 0, 0}, v1 = {0, 0, 0, 0, 0, 0, 0, 0};
      if (m0 + sr < M) {
        const u16* src = (const u16*)Ap + (size_t)(m0 + sr) * lda + k0 + sh;
        v0 = *(const u16x8*)src;
        v1 = *(const u16x8*)(src + 8);
      }
      *(u16x8*)&Ah[sr * LDT + sh] = v0;
      *(u16x8*)&Ah[sr * LDT + sh + 8] = v1;
    } else if (AMODE == 3) {
      u16x8 h0 = {0, 0, 0, 0, 0, 0, 0, 0}, h1 = h0, l0 = h0, l1 = h0;
      if (m0 + sr < M) {
        size_t base = (size_t)(m0 + sr) * lda + k0 + sh;
        h0 = *(const u16x8*)((const u16*)Ap + base);
        h1 = *(const u16x8*)((const u16*)Ap + base + 8);
        l0 = *(const u16x8*)(Apl + base);
        l1 = *(const u16x8*)(Apl + base + 8);
      }
      *(u16x8*)&Ah[sr * LDT + sh] = h0;
      *(u16x8*)&Ah[sr * LDT + sh + 8] = h1;
      *(u16x8*)&Al[sr * LDT + sh] = l0;
      *(u16x8*)&Al[sr * LDT + sh + 8] = l1;
    } else {  // AMODE 1 or 2: convert prefetched regs, then issue next loads
      u16x8 h0, h1, l0, l1;
#pragma unroll
      for (int i = 0; i < 8; i++) {
        u16 hb = f2bf(vals[i]);
        h0[i] = hb; l0[i] = f2bf(vals[i] - bf2f(hb));
        u16 hb2 = f2bf(vals[8 + i]);
        h1[i] = hb2; l1[i] = f2bf(vals[8 + i] - bf2f(hb2));
      }
      *(u16x8*)&Ah[sr * LDT + sh] = h0;
      *(u16x8*)&Ah[sr * LDT + sh + 8] = h1;
      *(u16x8*)&Al[sr * LDT + sh] = l0;
      *(u16x8*)&Al[sr * LDT + sh + 8] = l1;
      if (k0 + BK < K) loadA(k0 + BK);  // latency hides under stageB+barrier+MFMA
    }
    // ---- stage B ----
    {
      size_t base = (size_t)(n0 + sr) * K + k0 + sh;
      u16x8 b0 = *(const u16x8*)(Bph + base);
      u16x8 b1 = *(const u16x8*)(Bph + base + 8);
      *(u16x8*)&Bh[sr * LDT + sh] = b0;
      *(u16x8*)&Bh[sr * LDT + sh + 8] = b1;
      if (BSPLIT) {
        u16x8 c0 = *(const u16x8*)(Bpl + base);
        u16x8 c1 = *(const u16x8*)(Bpl + base + 8);
        *(u16x8*)&Bl[sr * LDT + sh] = c0;
        *(u16x8*)&Bl[sr * LDT + sh + 8] = c1;
      }
    }
    __syncthreads();
    // ---- fragments + MFMA ----
    const int fr = lane & 15;
    const int q8 = (lane >> 4) * 8;
    u16x8 af[4], bf[4];
#pragma unroll
    for (int i = 0; i < 4; i++) af[i] = *(const u16x8*)&Ah[(wm + i * 16 + fr) * LDT + q8];
#pragma unroll
    for (int j = 0; j < 4; j++) bf[j] = *(const u16x8*)&Bh[(wn + j * 16 + fr) * LDT + q8];
#pragma unroll
    for (int i = 0; i < 4; i++)
#pragma unroll
      for (int j = 0; j < 4; j++) acc[i][j] = mfma16(af[i], bf[j], acc[i][j]);
    if (ASPLIT) {
      u16x8 alf[4];
#pragma unroll
      for (int i = 0; i < 4; i++) alf[i] = *(const u16x8*)&Al[(wm + i * 16 + fr) * LDT + q8];
#pragma unroll
      for (int i = 0; i < 4; i++)
#pragma unroll
        for (int j = 0; j < 4; j++) acc[i][j] = mfma16(alf[i], bf[j], acc[i][j]);
    }
    if (BSPLIT) {
      u16x8 blf[4];
#pragma unroll
      for (int j = 0; j < 4; j++) blf[j] = *(const u16x8*)&Bl[(wn + j * 16 + fr) * LDT + q8];
#pragma unroll
      for (int i = 0; i < 4; i++)
#pragma unroll
        for (int j = 0; j < 4; j++) acc[i][j] = mfma16(af[i], blf[j], acc[i][j]);
    }
  }
  // ---- epilogue: C/D layout col=lane&15, row=(lane>>4)*4+reg (m89/m91 verified) ----
  const int fc = lane & 15;
  const int fr4 = (lane >> 4) * 4;
  if (FUSE) {
    // side: n0<512 -> S (0), n0==512 -> P (-1), n0>=640 -> O (1). Uniform per block.
    const int side = (n0 >= 640) ? 1 : (n0 < 512 ? 0 : -1);
    const int cb = n0 + wn + fc;
    float bvs[4];
#pragma unroll
    for (int j = 0; j < 4; j++) bvs[j] = biasf[cb + j * 16];
    __syncthreads();                 // staging LDS now dead; reuse Ah for score buf
    float* scb = (float*)Ah;         // [128 rows][2 wn-slots]
#pragma unroll
    for (int i = 0; i < 4; i++) {
#pragma unroll
      for (int rr = 0; rr < 4; rr++) {
        int rl = wm + i * 16 + fr4 + rr;
        int row = m0 + rl;
        float sc = 0.f;
        if (row < M) {
          const u16* arow = nullptr;
          if (side == 0) arow = auxp + (size_t)edges[(size_t)(r0 + row) * 2] * 512;
          else if (side == 1) arow = auxp + (size_t)edges[(size_t)(r0 + row) * 2 + 1] * 512;
#pragma unroll
          for (int j = 0; j < 4; j++) {
            int col = cb + j * 16;
            float v = acc[i][j][rr] + bvs[j];
            v = fmaxf(v, 0.f);
            if (side < 0) {
              Cf[(size_t)row * 128 + (col - 512)] = v;
            } else {
              int cc = col - (side ? 640 : 0);
              size_t ci = (size_t)row * 512 + cc;
              if (side) Ch2[ci] = f2bf(v);
              else Ch[ci] = f2bf(v);
              sc += v * bf2f(arow[cc]);
            }
          }
        }
        if (side >= 0) {
#pragma unroll
          for (int mm = 1; mm <= 8; mm <<= 1) sc += __shfl_xor(sc, mm, 64);
          if (fc == 0) scb[rl * 2 + (wn ? 1 : 0)] = sc;
        }
      }
    }
    __syncthreads();
    if (side >= 0 && tid < 128) {
      int row = m0 + tid;
      if (row < M) {
        float s = scb[tid * 2] + scb[tid * 2 + 1];
        atomicAdd(&scoresp[(side ? T_N : 0) + (r0 + row)], s);
      }
    }
    return;
  }
#pragma unroll
  for (int j = 0; j < 4; j++) {
    int col = n0 + wn + j * 16 + fc;
    float bv = biasf ? biasf[col] : 0.f;
#pragma unroll
    for (int i = 0; i < 4; i++) {
      int rbase = m0 + wm + i * 16 + fr4;
#pragma unroll
      for (int rr = 0; rr < 4; rr++) {
        int row = rbase + rr;
        if (row < M) {
          float v = acc[i][j][rr] + bv;
          if (RELU) v = fmaxf(v, 0.f);
          size_t ci = (size_t)row * ldc + col;
          if (OFLAGS & OF_F32) Cf[ci] = v;
          if (OFLAGS & OF_HI) {
            u16 h = f2bf(v);
            Ch[ci] = h;
            if (OFLAGS & OF_LO) Cl[ci] = f2bf(v - bf2f(h));
          }
        }
      }
    }
  }
}

// fp32 [K][N] -> bf16 hi(+lo) planes in BT form [N][K]. outl may be null.
__global__ void k_convT(const float* __restrict__ in, u16* __restrict__ outh,
                        u16* __restrict__ outl, int K, int N) {
  int idx = blockIdx.x * 256 + threadIdx.x;
  if (idx >= K * N) return;
  int n = idx / K, k = idx % K;
  float v = in[(size_t)k * N + n];
  u16 h = f2bf(v);
  outh[idx] = h;
  if (outl) outl[idx] = f2bf(v - bf2f(h));
}

// fp32 -> bf16 hi/lo planes, elementwise
__global__ void k_conv(const float* __restrict__ in, u16* __restrict__ outh,
                       u16* __restrict__ outl, int n) {
  int idx = blockIdx.x * 256 + threadIdx.x;
  if (idx >= n) return;
  float v = in[idx];
  u16 h = f2bf(v);
  outh[idx] = h;
  if (outl) outl[idx] = f2bf(v - bf2f(h));
}

// ---- weight folding (all fp32, trivial FLOPs) ----
__global__ void k_foldb1(const float* __restrict__ bp, const float* __restrict__ Ws,
                         const float* __restrict__ bs, float* __restrict__ bf1) {
  int n = blockIdx.x * 256 + threadIdx.x;
  if (n >= HID) return;
  float s = bs[n];
  for (int k = 0; k < HID; k++) s += bp[k] * Ws[(size_t)k * HID + n];
  bf1[n] = s;
}
__global__ void k_foldba(const float* __restrict__ bf1, const float* __restrict__ Ws,
                         float* __restrict__ ba) {
  int n = blockIdx.x * 256 + threadIdx.x;
  if (n >= HID) return;
  float s = 0.f;
  for (int k = 0; k < HID; k++) s += bf1[k] * Ws[(size_t)n * HID + k];
  ba[n] = s;
}
__global__ void k_foldwz(const float* __restrict__ Wf, const float* __restrict__ bs,
                         const float* __restrict__ bf1, float* __restrict__ wz,
                         float* __restrict__ bz) {
  int m = blockIdx.x * 256 + threadIdx.x;
  if (m < 128) {
    float s = 0.f;
    for (int n = 0; n < HID; n++) s += Wf[(size_t)m * HID + n] * bs[n];
    wz[m] = s;
  }
  if (m == 128) {
    float s = 0.f;
    for (int n = 0; n < HID; n++) s += bf1[n] * bs[n];
    *bz = s;
  }
}
// zs[o] = obj[o].wz + bz
__global__ void k_zsm(const float* __restrict__ obj, const float* __restrict__ wz,
                      const float* __restrict__ bz, float* __restrict__ zs, int rows) {
  int o = blockIdx.x * 4 + (threadIdx.x >> 6);
  int lane = threadIdx.x & 63;
  if (o >= rows) return;
  const float2* row = (const float2*)(obj + (size_t)o * 128);
  float2 v = row[lane];
  float2 w = ((const float2*)wz)[lane];
  float d = v.x * w.x + v.y * w.y;
  d = wave_sum(d);
  if (lane == 0) zs[o] = d + *bz;
}

__global__ void k_count(const int* __restrict__ edges, int* __restrict__ cnt) {
  int e = blockIdx.x * 256 + threadIdx.x;
  if (e >= 2 * T_N) return;
  int c = (e < T_N) ? edges[e * 2 + 0] : edges[(e - T_N) * 2 + 1];
  atomicAdd(cnt + c, 1);
}

__global__ void k_scan_a(const int* __restrict__ cnt, int* __restrict__ incl,
                         int* __restrict__ bsum) {
  __shared__ int sb[1024];
  int i = blockIdx.x * 1024 + threadIdx.x;
  int v = (i < O_N) ? cnt[i] : 0;
  sb[threadIdx.x] = v;
  __syncthreads();
  for (int ofs = 1; ofs < 1024; ofs <<= 1) {
    int t = (threadIdx.x >= ofs) ? sb[threadIdx.x - ofs] : 0;
    __syncthreads();
    sb[threadIdx.x] += t;
    __syncthreads();
  }
  if (i < O_N) incl[i] = sb[threadIdx.x];
  if (threadIdx.x == 1023) bsum[blockIdx.x] = sb[1023];
}

__global__ void k_scan_b(const int* __restrict__ bsum, int* __restrict__ bpre, int nb) {
  if (threadIdx.x == 0 && blockIdx.x == 0) {
    int run = 0;
    for (int b = 0; b < nb; b++) { bpre[b] = run; run += bsum[b]; }
  }
}

__global__ void k_scan_c(const int* __restrict__ incl, const int* __restrict__ cnt,
                         const int* __restrict__ bpre, int* __restrict__ excl,
                         int* __restrict__ cursor) {
  int i = blockIdx.x * 1024 + threadIdx.x;
  if (i >= O_N) return;
  int ex = incl[i] - cnt[i] + bpre[blockIdx.x];
  excl[i] = ex;
  cursor[i] = ex;
}

__global__ void k_fill(const int* __restrict__ edges, int* __restrict__ cursor,
                       int* __restrict__ csr) {
  int e = blockIdx.x * 256 + threadIdx.x;
  if (e >= 2 * T_N) return;
  int c = (e < T_N) ? edges[e * 2 + 0] : edges[(e - T_N) * 2 + 1];
  int pos = atomicAdd(cursor + c, 1);
  csr[pos] = e;
}

// scores[e] = zs[cand_idx[e]]  (base for fused-epilogue atomic accumulation)
__global__ void k_sinit(const int* __restrict__ edges, const float* __restrict__ zs,
                        float* __restrict__ scores) {
  int e = blockIdx.x * 256 + threadIdx.x;
  if (e >= 2 * T_N) return;
  int c = (e < T_N) ? edges[e * 2 + 0] : edges[(e - T_N) * 2 + 1];
  scores[e] = zs[c];
}

// score fix: scores[e] += cand_hi . (auxf - auxhi), per O-chunk
__global__ void k_fix(const u16* __restrict__ newShi, const u16* __restrict__ newOhi,
                      const u16* __restrict__ auxhi, const float* __restrict__ auxf,
                      const int* __restrict__ csr, const int* __restrict__ excl,
                      const int* __restrict__ cnt, float* __restrict__ scores,
                      int q0, int rows) {
  int ol = blockIdx.x * 4 + (threadIdx.x >> 6);
  int lane = threadIdx.x & 63;
  if (ol >= rows) return;
  int o = q0 + ol;
  int off = excl[o], deg = cnt[o];
  if (deg == 0) return;
  const f32x4* afp = (const f32x4*)(auxf + (size_t)ol * HID + lane * 8);
  f32x4 af0 = afp[0], af1 = afp[1];
  u16x8 ah = *(const u16x8*)(auxhi + (size_t)o * HID + lane * 8);
  float al[8];
#pragma unroll
  for (int k = 0; k < 4; k++) {
    al[k] = af0[k] - bf2f(ah[k]);
    al[4 + k] = af1[k] - bf2f(ah[4 + k]);
  }
  for (int i = 0; i < deg; i++) {
    int e = csr[off + i];
    const u16* cand =
        (e < T_N) ? newShi + (size_t)e * HID : newOhi + (size_t)(e - T_N) * HID;
    u16x8 ch = *(const u16x8*)(cand + lane * 8);
    float d = 0.f;
#pragma unroll
    for (int k = 0; k < 8; k++) d += bf2f(ch[k]) * al[k];
    d = wave_sum(d);
    if (lane == 0) scores[e] += d;  // each edge owned by exactly one object: no race
  }
}

// pool -> bf16 hi/lo planes (identical f2bf round points as the AMODE1 stage path)
__global__ void k_pool(const u16* __restrict__ newShi, const u16* __restrict__ newOhi,
                       const float* __restrict__ scores, const float* __restrict__ zs,
                       const int* __restrict__ csr, const int* __restrict__ excl,
                       const int* __restrict__ cnt, u16* __restrict__ pooledH,
                       u16* __restrict__ pooledL, int q0, int rows) {
  int ol = blockIdx.x * 4 + (threadIdx.x >> 6);
  int lane = threadIdx.x & 63;
  if (ol >= rows) return;
  int o = q0 + ol;
  int off = excl[o], deg = cnt[o];
  float zso = zs[o];
  float m = zso;
  for (int base = 0; base < deg; base += 64) {
    float s = (base + lane < deg) ? scores[csr[off + base + lane]] : -3.4e38f;
    m = fmaxf(m, s);
  }
#pragma unroll
  for (int x = 32; x >= 1; x >>= 1) m = fmaxf(m, __shfl_xor(m, x, 64));
  float denom = __expf(zso - m);
  float acc[8] = {0, 0, 0, 0, 0, 0, 0, 0};
  for (int i = 0; i < deg; i++) {
    int e = csr[off + i];
    float w = __expf(scores[e] - m);
    denom += w;
    const u16* cand =
        (e < T_N) ? newShi + (size_t)e * HID : newOhi + (size_t)(e - T_N) * HID;
    u16x8 cv = *(const u16x8*)(cand + lane * 8);
#pragma unroll
    for (int k = 0; k < 8; k++) acc[k] += w * bf2f(cv[k]);
  }
  float inv = 1.0f / denom;
  u16x8 ph, pl;
#pragma unroll
  for (int k = 0; k < 8; k++) {
    float v = acc[k] * inv;
    u16 h = f2bf(v);
    ph[k] = h;
    pl[k] = f2bf(v - bf2f(h));
  }
  *(u16x8*)(pooledH + (size_t)ol * HID + lane * 8) = ph;
  *(u16x8*)(pooledL + (size_t)ol * HID + lane * 8) = pl;
}

extern "C" void kernel_launch(void* const* d_in, const int* in_sizes, int n_in,
                              void* d_out, int out_size, void* d_ws, size_t ws_size,
                              hipStream_t stream) {
  const float* objf = (const float*)d_in[0];
  const float* predf = (const float*)d_in[1];
  const int* edges = (const int*)d_in[2];
  const float* n1w1f = (const float*)d_in[3];
  const float* n1b1f = (const float*)d_in[4];
  const float* n1w2f = (const float*)d_in[5];
  const float* n1b2f = (const float*)d_in[6];
  const float* n2w1f = (const float*)d_in[7];
  const float* n2b1f = (const float*)d_in[8];
  const float* n2w2f = (const float*)d_in[9];
  const float* n2b2f = (const float*)d_in[10];
  const float* projwf = (const float*)d_in[11];
  const float* projbf = (const float*)d_in[12];
  const float* simwf = (const float*)d_in[13];
  const float* simbf = (const float*)d_in[14];

  float* out_obj = (float*)d_out;                    // O x 128 fp32
  float* out_p = (float*)d_out + (size_t)O_N * 128;  // T x 128 fp32

  // ---- folded weights + fused M gemm with in-epilogue scores ----
  const long long FIXED = 267000000ll;
  long long budget = (long long)ws_size - FIXED;
  if (budget < 5000000ll) budget = 5000000ll;
  int rT, rOb, rFx;
  {
    long long r = budget / 2048; if (r > 50048) r = 50048; if (r < 1280) r = 1280;
    int n = (int)((T_N + r - 1) / r);
    rT = ((T_N + n - 1) / n + 127) & ~127;
  }
  {
    long long r = budget / 3072; if (r > 25024) r = 25024; if (r < 1280) r = 1280;
    int n = (int)((O_N + r - 1) / r);
    rOb = ((O_N + n - 1) / n + 127) & ~127;
  }
  {
    long long r = budget / 2048; if (r > 25024) r = 25024; if (r < 1280) r = 1280;
    int n = (int)((O_N + r - 1) / r);
    rFx = ((O_N + n - 1) / n + 127) & ~127;
  }
  const int nT = (T_N + rT - 1) / rT;
  const int nOb = (O_N + rOb - 1) / rOb;
  const int nFx = (O_N + rFx - 1) / rFx;
  size_t arena_sz = (size_t)rT * 2048;  // h1H + h1L
  if ((size_t)rFx * 2048 > arena_sz) arena_sz = (size_t)rFx * 2048;
  if ((size_t)rOb * 3072 > arena_sz) arena_sz = (size_t)rOb * 3072;
  arena_sz = (arena_sz + 4095) & ~(size_t)4095;

  char* ws = (char*)d_ws;
  size_t off = 0;
  u16* newShi = (u16*)(ws + off); off += (size_t)T_N * HID * 2;  // 102.4 MB
  u16* newOhi = (u16*)(ws + off); off += (size_t)T_N * HID * 2;  // 102.4 MB
  u16* auxhi = (u16*)(ws + off);  off += (size_t)O_N * HID * 2;  // 51.2 MB
  char* arena = ws + off; off += arena_sz;

  // phase M views
  u16* h1H = (u16*)arena;
  u16* h1L = (u16*)(arena + (size_t)rT * 1024);
  // fix-phase view
  float* auxfC = (float*)arena;
  // phase C views
  u16* pooledH = (u16*)arena;
  u16* pooledL = (u16*)(arena + (size_t)rOb * 1024);
  u16* h2c = (u16*)(arena + (size_t)rOb * 2048);

  float* scoresb = (float*)(ws + off); off += (size_t)2 * T_N * 4;
  float* zsb = (float*)(ws + off); off += (size_t)O_N * 4;
  int* cnt = (int*)(ws + off); off += (size_t)O_N * 4;
  int* incl = (int*)(ws + off); off += (size_t)O_N * 4;
  int* excl = (int*)(ws + off); off += (size_t)O_N * 4;
  int* cursor = (int*)(ws + off); off += (size_t)O_N * 4;
  int* csr = (int*)(ws + off); off += (size_t)2 * T_N * 4;
  int* bsum = (int*)(ws + off); off += 4096;
  int* bpre = (int*)(ws + off); off += 4096;
  u16* w1TH = (u16*)(ws + off); off += (size_t)K1 * HID * 2;
  u16* w1TL = (u16*)(ws + off); off += (size_t)K1 * HID * 2;
  u16* w2TH = (u16*)(ws + off); off += (size_t)1152 * HID * 2;
  u16* w2TL = (u16*)(ws + off); off += (size_t)1152 * HID * 2;
  u16* swTH = (u16*)(ws + off); off += (size_t)HID * HID * 2;
  u16* swTL = (u16*)(ws + off); off += (size_t)HID * HID * 2;
  u16* swRH = (u16*)(ws + off); off += (size_t)HID * HID * 2;
  u16* swRL = (u16*)(ws + off); off += (size_t)HID * HID * 2;
  u16* a2TH = (u16*)(ws + off); off += (size_t)HID * HID * 2;
  u16* a2TL = (u16*)(ws + off); off += (size_t)HID * HID * 2;
  u16* b2TH = (u16*)(ws + off); off += (size_t)128 * HID * 2;
  u16* b2TL = (u16*)(ws + off); off += (size_t)128 * HID * 2;
  float* Wf = (float*)(ws + off);  off += (size_t)128 * HID * 4;  // Wp@Ws
  float* Waf = (float*)(ws + off); off += (size_t)128 * HID * 4;  // Wf@Ws^T
  u16* WaTH = (u16*)(ws + off); off += (size_t)HID * 128 * 2;
  u16* WaTL = (u16*)(ws + off); off += (size_t)HID * 128 * 2;
  float* bf1 = (float*)(ws + off); off += 2048;
  float* baf = (float*)(ws + off); off += 2048;
  float* wzf = (float*)(ws + off); off += 512;
  float* bzf = (float*)(ws + off); off += 16;

  hipMemsetAsync(cnt, 0, O_N * sizeof(int), stream);

  // ---- weight planes ----
  k_convT<<<768, 256, 0, stream>>>(n1w1f, w1TH, w1TL, K1, HID);
  k_convT<<<2304, 256, 0, stream>>>(n1w2f, w2TH, w2TL, HID, 1152);
  k_convT<<<1024, 256, 0, stream>>>(simwf, swTH, swTL, HID, HID);
  k_conv<<<1024, 256, 0, stream>>>(simwf, swRH, swRL, HID * HID);  // Ws^T in BT form
  k_convT<<<1024, 256, 0, stream>>>(n2w1f, a2TH, a2TL, HID, HID);
  k_convT<<<256, 256, 0, stream>>>(n2w2f, b2TH, b2TL, HID, 128);

  // ---- CSR of cand_idx ----
  k_count<<<782, 256, 0, stream>>>(edges, cnt);
  k_scan_a<<<49, 1024, 0, stream>>>(cnt, incl, bsum);
  k_scan_b<<<1, 64, 0, stream>>>(bsum, bpre, 49);
  k_scan_c<<<49, 1024, 0, stream>>>(incl, cnt, bpre, excl, cursor);
  k_fill<<<782, 256, 0, stream>>>(edges, cursor, csr);

  // ---- weight folding ----
  {
    gemm_k<1, 1, 0, OF_F32, 0><<<4, 256, 0, stream>>>(
        projwf, nullptr, swTH, swTL, nullptr,
        Wf, nullptr, nullptr, nullptr,
        128, HID, HID, HID, HID, 4, nullptr, nullptr, nullptr, 0, nullptr, nullptr);
    gemm_k<1, 1, 0, OF_F32, 0><<<4, 256, 0, stream>>>(
        Wf, nullptr, swRH, swRL, nullptr,
        Waf, nullptr, nullptr, nullptr,
        128, HID, HID, HID, HID, 4, nullptr, nullptr, nullptr, 0, nullptr, nullptr);
    k_convT<<<256, 256, 0, stream>>>(Waf, WaTH, WaTL, 128, HID);
    k_foldb1<<<2, 256, 0, stream>>>(projbf, simwf, simbf, bf1);
    k_foldba<<<2, 256, 0, stream>>>(bf1, simwf, baf);
    k_foldwz<<<1, 256, 0, stream>>>(Wf, simbf, bf1, wzf, bzf);
  }

  // ---- phase B1 (folded): one full-grid gemm obj -> auxhi, plus zs matvec ----
  {
    int gx = (O_N + BM - 1) / BM;
    gemm_k<1, 1, 0, OF_HI, 0><<<gx * 4, 256, 0, stream>>>(
        objf, nullptr, WaTH, WaTL, baf,
        nullptr, auxhi, nullptr, nullptr,
        O_N, HID, 128, 128, HID, 4, nullptr, nullptr, nullptr, 0, nullptr, nullptr);
    k_zsm<<<(O_N + 3) / 4, 256, 0, stream>>>(objf, wzf, bzf, zsb, O_N);
  }

  // ---- scores base = zs[cand] (fused epilogues accumulate on top) ----
  k_sinit<<<782, 256, 0, stream>>>(edges, zsb, scoresb);

  // ---- phase M: MLP1 (gather gemm, reg-prefetched) + fused N=1152 gemm ----
  for (int ci = 0; ci < nT; ci++) {
    int r0 = ci * rT;
    int rows = (r0 + rT <= T_N) ? rT : (T_N - r0);
    int gx = (rows + BM - 1) / BM;
    gemm_k<2, 1, 1, OF_HI | OF_LO, 0><<<gx * 4, 256, 0, stream>>>(
        nullptr, nullptr, w1TH, w1TL, n1b1f,
        nullptr, h1H, h1L, nullptr,
        rows, HID, K1, 0, HID, 4, edges, objf, predf, r0, nullptr, nullptr);
    // fused: 0-511 -> newShi, 512-639 -> out_p, 640-1151 -> newOhi; scores atomic
    gemm_k<3, 1, 1, 0, 1><<<gx * 9, 256, 0, stream>>>(
        h1H, h1L, w2TH, w2TL, n1b2f,
        out_p + (size_t)r0 * 128, newShi + (size_t)r0 * HID, nullptr,
        newOhi + (size_t)r0 * HID,
        rows, 1152, HID, HID, HID, 9, edges, nullptr, nullptr, r0, auxhi, scoresb);
  }

  // ---- score fix: folded fp32 aux per O-chunk ----
  for (int ci = 0; ci < nFx; ci++) {
    int q0 = ci * rFx;
    int rows = (q0 + rFx <= O_N) ? rFx : (O_N - q0);
    int gx = (rows + BM - 1) / BM;
    gemm_k<1, 1, 0, OF_F32, 0><<<gx * 4, 256, 0, stream>>>(
        objf + (size_t)q0 * 128, nullptr, WaTH, WaTL, baf,
        auxfC, nullptr, nullptr, nullptr,
        rows, HID, 128, 128, HID, 4, nullptr, nullptr, nullptr, 0, nullptr, nullptr);
    k_fix<<<(rows + 3) / 4, 256, 0, stream>>>(
        newShi, newOhi, auxhi, auxfC, csr, excl, cnt, scoresb, q0, rows);
  }

  // ---- phase C: pool (bf16 planes) -> MLP2, O-chunks ----
  for (int ci = 0; ci < nOb; ci++) {
    int q0 = ci * rOb;
    int rows = (q0 + rOb <= O_N) ? rOb : (O_N - q0);
    int gx = (rows + BM - 1) / BM;
    k_pool<<<(rows + 3) / 4, 256, 0, stream>>>(
        newShi, newOhi, scoresb, zsb, csr, excl, cnt, pooledH, pooledL, q0, rows);
    gemm_k<3, 1, 1, OF_HI, 0><<<gx * 4, 256, 0, stream>>>(
        pooledH, pooledL, a2TH, a2TL, n2b1f,
        nullptr, h2c, nullptr, nullptr,
        rows, HID, HID, HID, HID, 4, nullptr, nullptr, nullptr, 0, nullptr, nullptr);
    gemm_k<0, 1, 1, OF_F32, 0><<<gx, 256, 0, stream>>>(
        h2c, nullptr, b2TH, b2TL, n2b2f,
        out_obj + (size_t)q0 * 128, nullptr, nullptr, nullptr,
        rows, 128, HID, HID, 128, 1, nullptr, nullptr, nullptr, 0, nullptr, nullptr);
  }

  (void)in_sizes; (void)n_in; (void)out_size;
}